// Round 1
// baseline (937.859 us; speedup 1.0000x reference)
//
#include <hip/hip_runtime.h>
#include <math.h>

// Problem constants (B=8, H=W=56, C=256)
#define CDIM 256
#define QKVDIM 768
#define NHEADS 8
#define DHEAD 32
#define NWIN 7
#define NREG 49
#define TK 4

static constexpr int NROWS = 8 * 56 * 56;  // 25088

__device__ __forceinline__ float gelu_f(float x) {
    float u = 0.7978845608028654f * (x + 0.044715f * x * x * x);
    return 0.5f * x * (1.0f + tanhf(u));
}

// ---------------- LayerNorm: one wave per row of 256 ----------------
__global__ __launch_bounds__(256) void ln_kernel(const float* __restrict__ x,
                                                 const float* __restrict__ g,
                                                 const float* __restrict__ bparam,
                                                 float* __restrict__ y) {
    int wave = threadIdx.x >> 6, lane = threadIdx.x & 63;
    int row = blockIdx.x * 4 + wave;
    const float4* xr = (const float4*)(x + (size_t)row * CDIM);
    float4 v = xr[lane];
    float s = v.x + v.y + v.z + v.w;
    float s2 = v.x * v.x + v.y * v.y + v.z * v.z + v.w * v.w;
#pragma unroll
    for (int off = 32; off; off >>= 1) {
        s += __shfl_xor(s, off, 64);
        s2 += __shfl_xor(s2, off, 64);
    }
    float mu = s * (1.0f / CDIM);
    float rstd = rsqrtf(s2 * (1.0f / CDIM) - mu * mu + 1e-5f);
    float4 gv = ((const float4*)g)[lane];
    float4 bv = ((const float4*)bparam)[lane];
    float4 o;
    o.x = (v.x - mu) * rstd * gv.x + bv.x;
    o.y = (v.y - mu) * rstd * gv.y + bv.y;
    o.z = (v.z - mu) * rstd * gv.z + bv.z;
    o.w = (v.w - mu) * rstd * gv.w + bv.w;
    ((float4*)(y + (size_t)row * CDIM))[lane] = o;
}

// ---------------- fp32 tiled GEMM: C = A@W + bias (+gelu) (+res) ----------------
// 64x64 tile, BK=16, 256 threads, 4x4 per thread.
template <bool GELU, bool RES>
__global__ __launch_bounds__(256) void gemm_kernel(const float* __restrict__ A,
                                                   const float* __restrict__ W,
                                                   const float* __restrict__ bias,
                                                   const float* __restrict__ res,
                                                   float* __restrict__ Cout,
                                                   int M, int N, int K) {
    __shared__ float As[16][68];  // padded: 68*4=272B row stride, 16B-aligned
    __shared__ float Bs[16][64];
    const int tid = threadIdx.x;
    const int tx = tid & 15, ty = tid >> 4;
    const int tile_m = blockIdx.y * 64, tile_n = blockIdx.x * 64;
    float acc[4][4] = {};
    for (int k0 = 0; k0 < K; k0 += 16) {
#pragma unroll
        for (int i = 0; i < 4; i++) {
            int e = tid + i * 256;
            As[e & 15][e >> 4] = A[(size_t)(tile_m + (e >> 4)) * K + k0 + (e & 15)];
        }
#pragma unroll
        for (int i = 0; i < 4; i++) {
            int e = tid + i * 256;
            Bs[e >> 6][e & 63] = W[(size_t)(k0 + (e >> 6)) * N + tile_n + (e & 63)];
        }
        __syncthreads();
#pragma unroll
        for (int kk = 0; kk < 16; kk++) {
            float4 a4 = *(const float4*)&As[kk][ty * 4];
            float4 b4 = *(const float4*)&Bs[kk][tx * 4];
            float av[4] = {a4.x, a4.y, a4.z, a4.w};
            float bv[4] = {b4.x, b4.y, b4.z, b4.w};
#pragma unroll
            for (int i = 0; i < 4; i++)
#pragma unroll
                for (int j = 0; j < 4; j++) acc[i][j] = fmaf(av[i], bv[j], acc[i][j]);
        }
        __syncthreads();
    }
    float4 bb = *(const float4*)&bias[tile_n + tx * 4];
#pragma unroll
    for (int i = 0; i < 4; i++) {
        size_t m = (size_t)tile_m + ty * 4 + i;
        size_t off = m * N + tile_n + tx * 4;
        float4 o;
        o.x = acc[i][0] + bb.x;
        o.y = acc[i][1] + bb.y;
        o.z = acc[i][2] + bb.z;
        o.w = acc[i][3] + bb.w;
        if (GELU) {
            o.x = gelu_f(o.x); o.y = gelu_f(o.y); o.z = gelu_f(o.z); o.w = gelu_f(o.w);
        }
        if (RES) {
            float4 rv = *(const float4*)&res[off];
            o.x += rv.x; o.y += rv.y; o.z += rv.z; o.w += rv.w;
        }
        *(float4*)&Cout[off] = o;
    }
}

// ---------------- region means of q and k ----------------
// grid: B*49 blocks, 256 threads (one per channel)
__global__ __launch_bounds__(256) void region_mean_kernel(const float* __restrict__ qkv,
                                                          float* __restrict__ qreg,
                                                          float* __restrict__ kreg) {
    int blk = blockIdx.x;
    int b = blk / NREG;
    int rid = blk % NREG;
    int ai = rid / NWIN, aj = rid % NWIN;
    int c = threadIdx.x;
    float sq = 0.f, sk = 0.f;
    for (int t = 0; t < 64; t++) {
        int bi = t >> 3, bj = t & 7;
        size_t row = ((size_t)b * 56 + ai * 8 + bi) * 56 + (aj * 8 + bj);
        sq += qkv[row * QKVDIM + c];
        sk += qkv[row * QKVDIM + CDIM + c];
    }
    qreg[(size_t)blk * CDIM + c] = sq * (1.0f / 64.0f);
    kreg[(size_t)blk * CDIM + c] = sk * (1.0f / 64.0f);
}

// ---------------- routing: logits row + top-4 (set) ----------------
// grid: B*49 blocks, 64 threads
__global__ __launch_bounds__(64) void routing_kernel(const float* __restrict__ qreg,
                                                     const float* __restrict__ kreg,
                                                     int* __restrict__ idx) {
    int b = blockIdx.x / NREG;
    int row = blockIdx.x % NREG;
    int lane = threadIdx.x;
    float myv = -INFINITY;
    if (lane < NREG) {
        const float* qv = qreg + ((size_t)b * NREG + row) * CDIM;
        const float* kv = kreg + ((size_t)b * NREG + lane) * CDIM;
        float s = 0.f;
        for (int c = 0; c < CDIM; c++) s += qv[c] * kv[c];
        myv = s;
    }
    for (int t = 0; t < TK; t++) {
        float v = myv;
        int ix = lane;
#pragma unroll
        for (int off = 32; off; off >>= 1) {
            float ov = __shfl_xor(v, off, 64);
            int oi = __shfl_xor(ix, off, 64);
            if (ov > v || (ov == v && oi < ix)) { v = ov; ix = oi; }
        }
        if (lane == 0) idx[((size_t)b * NREG + row) * TK + t] = ix;
        if (lane == ix) myv = -INFINITY;
    }
}

// ---------------- attention per (b, region, head) ----------------
// 256 threads: 4 lanes per q-row; each lane owns 64 of the 256 keys.
__global__ __launch_bounds__(256) void attn_kernel(const float* __restrict__ qkv,
                                                   const int* __restrict__ idx,
                                                   float* __restrict__ out) {
    int blk = blockIdx.x;
    int hd = blk % NHEADS;
    int br = blk / NHEADS;
    int rid = br % NREG;
    int b = br / NREG;
    int ai = rid / NWIN, aj = rid % NWIN;

    __shared__ float q_s[64][36];   // stride 36 floats = 144B (16B-aligned, conflict-lite)
    __shared__ float kv_s[64][36];

    const int tid = threadIdx.x;
    // stage q: token t = tid/4, 8 floats at offset (tid%4)*8
    {
        int t = tid >> 2;
        int o = (tid & 3) * 8;
        size_t row = ((size_t)b * 56 + ai * 8 + (t >> 3)) * 56 + (aj * 8 + (t & 7));
        const float4* src = (const float4*)(qkv + row * QKVDIM + hd * DHEAD + o);
        float4 a0 = src[0], a1 = src[1];
        *(float4*)&q_s[t][o] = a0;
        *(float4*)&q_s[t][o + 4] = a1;
    }
    __syncthreads();

    const int qrow = tid >> 2;
    const int m = tid & 3;
    float qv[DHEAD];
#pragma unroll
    for (int dd = 0; dd < DHEAD; dd++) qv[dd] = q_s[qrow][dd];

    const int* ip = idx + ((size_t)b * NREG + rid) * TK;
    int topidx[4] = {ip[0], ip[1], ip[2], ip[3]};

    float sc[64];
    const float scale = 0.17677669529663687f;  // 1/sqrt(32)

#pragma unroll
    for (int rc = 0; rc < 4; rc++) {
        int reg = topidx[rc];
        int rai = reg / NWIN, raj = reg % NWIN;
        __syncthreads();
        {
            int t = tid >> 2;
            int o = (tid & 3) * 8;
            size_t row = ((size_t)b * 56 + rai * 8 + (t >> 3)) * 56 + (raj * 8 + (t & 7));
            const float4* src = (const float4*)(qkv + row * QKVDIM + CDIM + hd * DHEAD + o);
            float4 a0 = src[0], a1 = src[1];
            *(float4*)&kv_s[t][o] = a0;
            *(float4*)&kv_s[t][o + 4] = a1;
        }
        __syncthreads();
#pragma unroll
        for (int j = 0; j < 16; j++) {
            int key = m + j * 4;
            float s = 0.f;
#pragma unroll
            for (int dd = 0; dd < DHEAD; dd++) s = fmaf(qv[dd], kv_s[key][dd], s);
            sc[rc * 16 + j] = s * scale;
        }
    }

    // softmax over 256 keys: 64 local + 4 lanes of this row (xor 1,2)
    float mx = -INFINITY;
#pragma unroll
    for (int i = 0; i < 64; i++) mx = fmaxf(mx, sc[i]);
    mx = fmaxf(mx, __shfl_xor(mx, 1, 64));
    mx = fmaxf(mx, __shfl_xor(mx, 2, 64));
    float sum = 0.f;
#pragma unroll
    for (int i = 0; i < 64; i++) {
        sc[i] = __expf(sc[i] - mx);
        sum += sc[i];
    }
    sum += __shfl_xor(sum, 1, 64);
    sum += __shfl_xor(sum, 2, 64);
    float inv = 1.0f / sum;
#pragma unroll
    for (int i = 0; i < 64; i++) sc[i] *= inv;

    float ov[DHEAD] = {};
#pragma unroll
    for (int rc = 0; rc < 4; rc++) {
        int reg = topidx[rc];
        int rai = reg / NWIN, raj = reg % NWIN;
        __syncthreads();
        {
            int t = tid >> 2;
            int o = (tid & 3) * 8;
            size_t row = ((size_t)b * 56 + rai * 8 + (t >> 3)) * 56 + (raj * 8 + (t & 7));
            const float4* src = (const float4*)(qkv + row * QKVDIM + 2 * CDIM + hd * DHEAD + o);
            float4 a0 = src[0], a1 = src[1];
            *(float4*)&kv_s[t][o] = a0;
            *(float4*)&kv_s[t][o + 4] = a1;
        }
        __syncthreads();
#pragma unroll
        for (int j = 0; j < 16; j++) {
            int key = m + j * 4;
            float p = sc[rc * 16 + j];
#pragma unroll
            for (int dd = 0; dd < DHEAD; dd++) ov[dd] = fmaf(p, kv_s[key][dd], ov[dd]);
        }
    }
#pragma unroll
    for (int dd = 0; dd < DHEAD; dd++) {
        ov[dd] += __shfl_xor(ov[dd], 1, 64);
        ov[dd] += __shfl_xor(ov[dd], 2, 64);
    }
    // write 8 floats: dims [m*8, m*8+8) of row qrow (static indexing via branch)
    {
        size_t row = ((size_t)b * 56 + ai * 8 + (qrow >> 3)) * 56 + (aj * 8 + (qrow & 7));
        float* dst = out + row * CDIM + hd * DHEAD + m * 8;
        float4 o0, o1;
        if (m == 0) {
            o0 = make_float4(ov[0], ov[1], ov[2], ov[3]);
            o1 = make_float4(ov[4], ov[5], ov[6], ov[7]);
        } else if (m == 1) {
            o0 = make_float4(ov[8], ov[9], ov[10], ov[11]);
            o1 = make_float4(ov[12], ov[13], ov[14], ov[15]);
        } else if (m == 2) {
            o0 = make_float4(ov[16], ov[17], ov[18], ov[19]);
            o1 = make_float4(ov[20], ov[21], ov[22], ov[23]);
        } else {
            o0 = make_float4(ov[24], ov[25], ov[26], ov[27]);
            o1 = make_float4(ov[28], ov[29], ov[30], ov[31]);
        }
        *(float4*)dst = o0;
        *(float4*)(dst + 4) = o1;
    }
}

extern "C" void kernel_launch(void* const* d_in, const int* in_sizes, int n_in,
                              void* d_out, int out_size, void* d_ws, size_t ws_size,
                              hipStream_t stream) {
    const float* x    = (const float*)d_in[0];
    const float* ln1g = (const float*)d_in[1];
    const float* ln1b = (const float*)d_in[2];
    const float* wqkv = (const float*)d_in[3];
    const float* bqkv = (const float*)d_in[4];
    const float* wo   = (const float*)d_in[5];
    const float* bo   = (const float*)d_in[6];
    const float* ln2g = (const float*)d_in[7];
    const float* ln2b = (const float*)d_in[8];
    const float* w1   = (const float*)d_in[9];
    const float* bm1  = (const float*)d_in[10];
    const float* w2   = (const float*)d_in[11];
    const float* bm2  = (const float*)d_in[12];
    float* out = (float*)d_out;
    char* ws = (char*)d_ws;

    const int M = NROWS;  // 25088
    // workspace layout (bytes):
    //   y:    [0, 25690112)            LN1 out, later LN2 out
    //   attn: [25690112, 51380224)     attention output (spatial)
    //   qreg: [51380224, 51781632)
    //   kreg: [51781632, 52183040)
    //   idx:  [52183040, 52191232)
    //   big:  [52191232, +102760448)   qkv (77MB) aliased with mlp hidden (103MB)
    // x1 (residual-1 output) lives in d_out. Total ws: ~148 MB.
    float* ws_y    = (float*)(ws);
    float* ws_attn = (float*)(ws + 25690112);
    float* ws_qreg = (float*)(ws + 51380224);
    float* ws_kreg = (float*)(ws + 51781632);
    int*   ws_idx  = (int*)(ws + 52183040);
    float* ws_big  = (float*)(ws + 52191232);

    // 1) y = LN1(x)
    ln_kernel<<<M / 4, 256, 0, stream>>>(x, ln1g, ln1b, ws_y);
    // 2) qkv = y @ wqkv + bqkv
    gemm_kernel<false, false><<<dim3(QKVDIM / 64, M / 64), 256, 0, stream>>>(
        ws_y, wqkv, bqkv, nullptr, ws_big, M, QKVDIM, CDIM);
    // 3) region means
    region_mean_kernel<<<8 * NREG, 256, 0, stream>>>(ws_big, ws_qreg, ws_kreg);
    // 4) routing top-4
    routing_kernel<<<8 * NREG, 64, 0, stream>>>(ws_qreg, ws_kreg, ws_idx);
    // 5) attention
    attn_kernel<<<8 * NREG * NHEADS, 256, 0, stream>>>(ws_big, ws_idx, ws_attn);
    // 6) x1 = x + attn @ wo + bo    (into d_out)
    gemm_kernel<false, true><<<dim3(CDIM / 64, M / 64), 256, 0, stream>>>(
        ws_attn, wo, bo, x, out, M, CDIM, CDIM);
    // 7) z = LN2(x1)
    ln_kernel<<<M / 4, 256, 0, stream>>>(out, ln2g, ln2b, ws_y);
    // 8) h = gelu(z @ w1 + bm1)
    gemm_kernel<true, false><<<dim3(1024 / 64, M / 64), 256, 0, stream>>>(
        ws_y, w1, bm1, nullptr, ws_big, M, 1024, CDIM);
    // 9) out = x1 + h @ w2 + bm2
    gemm_kernel<false, true><<<dim3(CDIM / 64, M / 64), 256, 0, stream>>>(
        ws_big, w2, bm2, out, out, M, CDIM, 1024);
}

// Round 4
// 333.162 us; speedup vs baseline: 2.8150x; 2.8150x over previous
//
#include <hip/hip_runtime.h>
#include <math.h>

#define CDIM 256
#define QKVDIM 768
#define NHEADS 8
#define DHEAD 32
#define NWIN 7
#define NREG 49
#define TK 4
static constexpr int NROWS = 8 * 56 * 56;  // 25088

typedef __attribute__((ext_vector_type(8))) short s16x8;
typedef __attribute__((ext_vector_type(4))) float f32x4;
typedef __attribute__((ext_vector_type(16))) float f32x16;
typedef unsigned short ushort_t;

union U4 { unsigned u[4]; s16x8 v; };

__device__ __forceinline__ ushort_t bfr(float f) {  // fp32 -> bf16 RNE
    unsigned u = __float_as_uint(f);
    unsigned r = (u + 0x7FFFu + ((u >> 16) & 1u)) >> 16;
    return (ushort_t)r;
}
__device__ __forceinline__ float gelu_f(float x) {
    float u = 0.7978845608028654f * (x + 0.044715f * x * x * x);
    return 0.5f * x * (1.0f + tanhf(u));
}
__device__ __forceinline__ void glds16(const void* g, void* l) {
    __builtin_amdgcn_global_load_lds((const __attribute__((address_space(1))) void*)g,
                                     (__attribute__((address_space(3))) void*)l, 16, 0, 0);
}
__device__ __forceinline__ f32x16 zero16() {
    f32x16 z;
#pragma unroll
    for (int i = 0; i < 16; i++) z[i] = 0.f;
    return z;
}

// ---------------- LayerNorm: fp32 in -> bf16 out. one wave per row ----------------
__global__ __launch_bounds__(256) void ln_kernel(const float* __restrict__ x,
                                                 const float* __restrict__ g,
                                                 const float* __restrict__ bparam,
                                                 ushort_t* __restrict__ y) {
    int wave = threadIdx.x >> 6, lane = threadIdx.x & 63;
    int row = blockIdx.x * 4 + wave;
    const float4* xr = (const float4*)(x + (size_t)row * CDIM);
    float4 v = xr[lane];
    float s = v.x + v.y + v.z + v.w;
    float s2 = v.x * v.x + v.y * v.y + v.z * v.z + v.w * v.w;
#pragma unroll
    for (int off = 32; off; off >>= 1) {
        s += __shfl_xor(s, off, 64);
        s2 += __shfl_xor(s2, off, 64);
    }
    float mu = s * (1.0f / CDIM);
    float rstd = rsqrtf(s2 * (1.0f / CDIM) - mu * mu + 1e-5f);
    float4 gv = ((const float4*)g)[lane];
    float4 bv = ((const float4*)bparam)[lane];
    ushort4 o;
    o.x = bfr((v.x - mu) * rstd * gv.x + bv.x);
    o.y = bfr((v.y - mu) * rstd * gv.y + bv.y);
    o.z = bfr((v.z - mu) * rstd * gv.z + bv.z);
    o.w = bfr((v.w - mu) * rstd * gv.w + bv.w);
    *(ushort4*)(y + (size_t)row * CDIM + lane * 4) = o;
}

// ---------------- f32 region means of LN1(x): ymean[b*49+r][256] ----------------
// block = one region (64 tokens); wave w handles tokens w,w+4,...; per-lane 4 channels.
__global__ __launch_bounds__(256) void ymean_kernel(const float* __restrict__ x,
                                                    const float* __restrict__ g,
                                                    const float* __restrict__ bparam,
                                                    float* __restrict__ ymean) {
    int blk = blockIdx.x;  // b*49 + rid
    int b = blk / NREG, rid = blk % NREG;
    int ai = rid / NWIN, aj = rid % NWIN;
    int w = threadIdx.x >> 6, lane = threadIdx.x & 63;
    float4 gv = ((const float4*)g)[lane];
    float4 bv = ((const float4*)bparam)[lane];
    float4 acc = {0.f, 0.f, 0.f, 0.f};
    for (int it = 0; it < 16; it++) {
        int t = it * 4 + w;
        size_t row = ((size_t)(b * 56 + ai * 8 + (t >> 3))) * 56 + aj * 8 + (t & 7);
        float4 v = ((const float4*)(x + row * CDIM))[lane];
        float s = v.x + v.y + v.z + v.w;
        float s2 = v.x * v.x + v.y * v.y + v.z * v.z + v.w * v.w;
#pragma unroll
        for (int off = 32; off; off >>= 1) {
            s += __shfl_xor(s, off, 64);
            s2 += __shfl_xor(s2, off, 64);
        }
        float mu = s * (1.0f / CDIM);
        float rstd = rsqrtf(s2 * (1.0f / CDIM) - mu * mu + 1e-5f);
        acc.x += (v.x - mu) * rstd * gv.x + bv.x;
        acc.y += (v.y - mu) * rstd * gv.y + bv.y;
        acc.z += (v.z - mu) * rstd * gv.z + bv.z;
        acc.w += (v.w - mu) * rstd * gv.w + bv.w;
    }
    __shared__ float red[4][CDIM];
    *(float4*)&red[w][lane * 4] = acc;
    __syncthreads();
    if (w == 0) {
        float4 r0 = *(float4*)&red[0][lane * 4];
        float4 r1 = *(float4*)&red[1][lane * 4];
        float4 r2 = *(float4*)&red[2][lane * 4];
        float4 r3 = *(float4*)&red[3][lane * 4];
        float4 o;
        o.x = (r0.x + r1.x + r2.x + r3.x) * (1.0f / 64.0f);
        o.y = (r0.y + r1.y + r2.y + r3.y) * (1.0f / 64.0f);
        o.z = (r0.z + r1.z + r2.z + r3.z) * (1.0f / 64.0f);
        o.w = (r0.w + r1.w + r2.w + r3.w) * (1.0f / 64.0f);
        *(float4*)(ymean + (size_t)blk * CDIM + lane * 4) = o;
    }
}

// ---------------- f32 projection of region means: qreg/kreg ----------------
__global__ __launch_bounds__(256) void regproj_kernel(const float* __restrict__ ymean,
                                                      const float* __restrict__ wqkv,
                                                      const float* __restrict__ bqkv,
                                                      float* __restrict__ qreg,
                                                      float* __restrict__ kreg) {
    int blk = blockIdx.x;
    __shared__ float ym[CDIM];
    ym[threadIdx.x] = ymean[(size_t)blk * CDIM + threadIdx.x];
    __syncthreads();
    int c = threadIdx.x;
    float sq = 0.f, sk = 0.f;
    for (int k = 0; k < CDIM; k++) {
        float yv = ym[k];
        sq = fmaf(yv, wqkv[(size_t)k * QKVDIM + c], sq);
        sk = fmaf(yv, wqkv[(size_t)k * QKVDIM + CDIM + c], sk);
    }
    qreg[(size_t)blk * CDIM + c] = sq + bqkv[c];
    kreg[(size_t)blk * CDIM + c] = sk + bqkv[CDIM + c];
}

// ---------------- weight transpose: f32 [K][N] -> bf16 [N][K] ----------------
__global__ __launch_bounds__(256) void wtrans_kernel(const float* __restrict__ src,
                                                     ushort_t* __restrict__ dst,
                                                     int K, int N) {
    __shared__ float t[32][33];
    int tx = threadIdx.x & 31, ty = threadIdx.x >> 5;
    int n0 = blockIdx.x * 32, k0 = blockIdx.y * 32;
#pragma unroll
    for (int i = 0; i < 4; i++) t[ty + i * 8][tx] = src[(size_t)(k0 + ty + i * 8) * N + n0 + tx];
    __syncthreads();
#pragma unroll
    for (int i = 0; i < 4; i++)
        dst[(size_t)(n0 + ty + i * 8) * K + k0 + tx] = bfr(t[tx][ty + i * 8]);
}

// ---------------- v^T: bf16 qkv v-slice -> vt [b][c=256][t=3136] ----------------
__global__ __launch_bounds__(256) void vtrans_kernel(const ushort_t* __restrict__ qkvbf,
                                                     ushort_t* __restrict__ vt) {
    __shared__ ushort_t t[32][34];
    int tx = threadIdx.x & 31, ty = threadIdx.x >> 5;
    int t0 = blockIdx.x * 32, c0 = blockIdx.y * 32, b = blockIdx.z;
#pragma unroll
    for (int i = 0; i < 4; i++)
        t[ty + i * 8][tx] = qkvbf[((size_t)b * 3136 + t0 + ty + i * 8) * QKVDIM + 512 + c0 + tx];
    __syncthreads();
#pragma unroll
    for (int i = 0; i < 4; i++)
        vt[((size_t)b * CDIM + c0 + ty + i * 8) * 3136 + t0 + tx] = t[tx][ty + i * 8];
}

// ---------------- bf16 MFMA GEMM: C = A@WT^T + bias, epilogue variants -------------
// A: [M][K] bf16, WT: [N][K] bf16. 128x128 tile, BK=64, 4 waves, 16x16x32 MFMA.
// MODE 0: out bf16 [M][768], cols<256 scaled by 1/sqrt(32)
// MODE 1/3: out f32 = v + bias + res
// MODE 2: out bf16 = gelu(v + bias)
template <int MODE>
__global__ __launch_bounds__(256) void mgemm(const ushort_t* __restrict__ A,
                                             const ushort_t* __restrict__ WT,
                                             const float* __restrict__ bias,
                                             const float* __restrict__ res,
                                             float* __restrict__ outf,
                                             ushort_t* __restrict__ outb,
                                             int N, int K) {
    __shared__ __align__(16) ushort_t As[128 * 64];
    __shared__ __align__(16) ushort_t Bs[128 * 64];
    const int tid = threadIdx.x, lane = tid & 63, w = tid >> 6;
    const int wm = w >> 1, wn = w & 1;
    const int tm = blockIdx.y * 128, tn = blockIdx.x * 128;
    f32x4 acc[4][4];
#pragma unroll
    for (int i = 0; i < 4; i++)
#pragma unroll
        for (int j = 0; j < 4; j++) acc[i][j] = (f32x4){0.f, 0.f, 0.f, 0.f};

    for (int k0 = 0; k0 < K; k0 += 64) {
        __syncthreads();
#pragma unroll
        for (int p = 0; p < 4; p++) {
            int row = (p * 4 + w) * 8 + (lane >> 3);
            int slot = lane & 7;
            glds16(A + (size_t)(tm + row) * K + k0 + ((slot ^ (row & 7)) * 8),
                   (char*)As + (p * 4 + w) * 1024);
            glds16(WT + (size_t)(tn + row) * K + k0 + ((slot ^ (row & 7)) * 8),
                   (char*)Bs + (p * 4 + w) * 1024);
        }
        __syncthreads();
#pragma unroll
        for (int kk = 0; kk < 2; kk++) {
            s16x8 af[4], bfv[4];
#pragma unroll
            for (int i = 0; i < 4; i++) {
                int rowa = wm * 64 + i * 16 + (lane & 15);
                af[i] = *(const s16x8*)&As[rowa * 64 + (((kk * 4 + (lane >> 4)) ^ (rowa & 7)) * 8)];
                int rowb = wn * 64 + i * 16 + (lane & 15);
                bfv[i] = *(const s16x8*)&Bs[rowb * 64 + (((kk * 4 + (lane >> 4)) ^ (rowb & 7)) * 8)];
            }
#pragma unroll
            for (int i = 0; i < 4; i++)
#pragma unroll
                for (int j = 0; j < 4; j++)
                    acc[i][j] = __builtin_amdgcn_mfma_f32_16x16x32_bf16(af[i], bfv[j], acc[i][j], 0, 0, 0);
        }
    }
    const int cl = lane & 15, gq = lane >> 4;
#pragma unroll
    for (int j = 0; j < 4; j++) {
        int col = tn + wn * 64 + j * 16 + cl;
        float bb = bias[col];
#pragma unroll
        for (int i = 0; i < 4; i++) {
            int rowb = tm + wm * 64 + i * 16 + gq * 4;
#pragma unroll
            for (int r = 0; r < 4; r++) {
                float v = acc[i][j][r] + bb;
                size_t off = (size_t)(rowb + r) * N + col;
                if (MODE == 0) {
                    outb[off] = bfr(col < 256 ? v * 0.17677669529663687f : v);
                } else if (MODE == 1 || MODE == 3) {
                    outf[off] = v + res[off];
                } else {
                    outb[off] = bfr(gelu_f(v));
                }
            }
        }
    }
}

// ---------------- routing top-4 (set) ----------------
__global__ __launch_bounds__(64) void routing_kernel(const float* __restrict__ qreg,
                                                     const float* __restrict__ kreg,
                                                     int* __restrict__ idx) {
    int b = blockIdx.x / NREG;
    int row = blockIdx.x % NREG;
    int lane = threadIdx.x;
    float myv = -INFINITY;
    if (lane < NREG) {
        const float* qv = qreg + ((size_t)b * NREG + row) * CDIM;
        const float* kv = kreg + ((size_t)b * NREG + lane) * CDIM;
        float s = 0.f;
        for (int c = 0; c < CDIM; c++) s += qv[c] * kv[c];
        myv = s;
    }
    for (int t = 0; t < TK; t++) {
        float v = myv;
        int ix = lane;
#pragma unroll
        for (int off = 32; off; off >>= 1) {
            float ov = __shfl_xor(v, off, 64);
            int oi = __shfl_xor(ix, off, 64);
            if (ov > v || (ov == v && oi < ix)) { v = ov; ix = oi; }
        }
        if (lane == 0) idx[((size_t)b * NREG + row) * TK + t] = ix;
        if (lane == ix) myv = -INFINITY;
    }
}

// ---------------- MFMA flash attention, fully in-register ----------------
// wave = (b, region, head, q-half). S^T = mfma(K, Q) 32x32x16; softmax in-register;
// P repack via cvt+shfl_xor(32); PV from global V^T. No LDS, no barriers.
__global__ __launch_bounds__(256) void attn2_kernel(const ushort_t* __restrict__ qk,
                                                    const ushort_t* __restrict__ vt,
                                                    const int* __restrict__ idx,
                                                    ushort_t* __restrict__ outb) {
    int wid = blockIdx.x * 4 + (threadIdx.x >> 6);
    int lane = threadIdx.x & 63;
    int g = lane >> 5, col = lane & 31;
    int qh = wid & 1;
    int h = (wid >> 1) & 7;
    int rr = wid >> 4;  // b*49 + rid
    int rid = rr % NREG, b = rr / NREG;
    int ai = rid / NWIN, aj = rid % NWIN;

    int qtok = qh * 32 + col;
    size_t qrow_g = ((size_t)(b * 56 + ai * 8 + (qtok >> 3))) * 56 + aj * 8 + (qtok & 7);
    const s16x8 bq0 = *(const s16x8*)(qk + qrow_g * QKVDIM + h * 32 + g * 8);
    const s16x8 bq1 = *(const s16x8*)(qk + qrow_g * QKVDIM + h * 32 + 16 + g * 8);

    const int* ip = idx + (size_t)rr * TK;
    int regs[4] = {ip[0], ip[1], ip[2], ip[3]};

    float m_run = -1e30f, l_run = 0.f;
    f32x16 o = zero16();
    const size_t vtrowbase = ((size_t)(b * CDIM + h * 32 + col)) * 3136;

#pragma unroll
    for (int rc = 0; rc < 4; rc++) {
        int reg = regs[rc];
        int rai = reg / NWIN, raj = reg % NWIN;
        s16x8 ka[2][2];
#pragma unroll
        for (int mf = 0; mf < 2; mf++) {
            int ktok = mf * 32 + col;
            size_t krow_g = ((size_t)(b * 56 + rai * 8 + (ktok >> 3))) * 56 + raj * 8 + (ktok & 7);
#pragma unroll
            for (int kd = 0; kd < 2; kd++)
                ka[mf][kd] = *(const s16x8*)(qk + krow_g * QKVDIM + 256 + h * 32 + kd * 16 + g * 8);
        }
        f32x16 s0 = zero16(), s1 = zero16();
        s0 = __builtin_amdgcn_mfma_f32_32x32x16_bf16(ka[0][0], bq0, s0, 0, 0, 0);
        s0 = __builtin_amdgcn_mfma_f32_32x32x16_bf16(ka[0][1], bq1, s0, 0, 0, 0);
        s1 = __builtin_amdgcn_mfma_f32_32x32x16_bf16(ka[1][0], bq0, s1, 0, 0, 0);
        s1 = __builtin_amdgcn_mfma_f32_32x32x16_bf16(ka[1][1], bq1, s1, 0, 0, 0);

        float tmax = -1e30f;
#pragma unroll
        for (int i = 0; i < 16; i++) tmax = fmaxf(tmax, fmaxf(s0[i], s1[i]));
        tmax = fmaxf(tmax, __shfl_xor(tmax, 32, 64));

        // online softmax (always rescale; P <= 1 for bf16 accuracy)
        float m_new = fmaxf(m_run, tmax);
        float f = __expf(m_run - m_new);
        l_run *= f;
#pragma unroll
        for (int r = 0; r < 16; r++) {
            int orow = (r & 3) + 8 * (r >> 2) + 4 * g;
            float fr = __shfl(f, orow, 64);
            o[r] *= fr;
        }
        m_run = m_new;

        float tsum = 0.f;
#pragma unroll
        for (int i = 0; i < 16; i++) {
            s0[i] = __expf(s0[i] - m_run);
            s1[i] = __expf(s1[i] - m_run);
            tsum += s0[i] + s1[i];
        }
        l_run += tsum + __shfl_xor(tsum, 32, 64);

#define PVSTEP(SS, CC, KS)                                                              \
    {                                                                                   \
        unsigned wa = (unsigned)bfr(SS[CC * 8 + 0]) | ((unsigned)bfr(SS[CC * 8 + 1]) << 16); \
        unsigned wb_ = (unsigned)bfr(SS[CC * 8 + 2]) | ((unsigned)bfr(SS[CC * 8 + 3]) << 16); \
        unsigned wc = (unsigned)bfr(SS[CC * 8 + 4]) | ((unsigned)bfr(SS[CC * 8 + 5]) << 16); \
        unsigned wd = (unsigned)bfr(SS[CC * 8 + 6]) | ((unsigned)bfr(SS[CC * 8 + 7]) << 16); \
        unsigned sxa = (unsigned)__shfl_xor((int)wa, 32, 64);                           \
        unsigned sxb = (unsigned)__shfl_xor((int)wb_, 32, 64);                          \
        unsigned sxc = (unsigned)__shfl_xor((int)wc, 32, 64);                           \
        unsigned sxd = (unsigned)__shfl_xor((int)wd, 32, 64);                           \
        U4 pw;                                                                          \
        pw.u[0] = g ? sxc : wa;                                                         \
        pw.u[1] = g ? sxd : wb_;                                                        \
        pw.u[2] = g ? wc : sxa;                                                         \
        pw.u[3] = g ? wd : sxb;                                                         \
        const s16x8 vb = *(const s16x8*)(vt + vtrowbase + (size_t)(rai * 8 + KS * 2 + g) * 56 + raj * 8); \
        o = __builtin_amdgcn_mfma_f32_32x32x16_bf16(pw.v, vb, o, 0, 0, 0);              \
    }
        PVSTEP(s0, 0, 0)
        PVSTEP(s0, 1, 1)
        PVSTEP(s1, 0, 2)
        PVSTEP(s1, 1, 3)
#undef PVSTEP
    }

#pragma unroll
    for (int r = 0; r < 16; r++) {
        int orow = (r & 3) + 8 * (r >> 2) + 4 * g;
        float lr = __shfl(l_run, orow, 64);
        float val = o[r] / lr;
        int tok = qh * 32 + orow;
        size_t row_g = ((size_t)(b * 56 + ai * 8 + (tok >> 3))) * 56 + aj * 8 + (tok & 7);
        outb[row_g * 256 + h * 32 + col] = bfr(val);
    }
}

extern "C" void kernel_launch(void* const* d_in, const int* in_sizes, int n_in,
                              void* d_out, int out_size, void* d_ws, size_t ws_size,
                              hipStream_t stream) {
    const float* x    = (const float*)d_in[0];
    const float* ln1g = (const float*)d_in[1];
    const float* ln1b = (const float*)d_in[2];
    const float* wqkv = (const float*)d_in[3];
    const float* bqkv = (const float*)d_in[4];
    const float* wo   = (const float*)d_in[5];
    const float* bo   = (const float*)d_in[6];
    const float* ln2g = (const float*)d_in[7];
    const float* ln2b = (const float*)d_in[8];
    const float* w1   = (const float*)d_in[9];
    const float* bm1  = (const float*)d_in[10];
    const float* w2   = (const float*)d_in[11];
    const float* bm2  = (const float*)d_in[12];
    float* out = (float*)d_out;
    char* ws = (char*)d_ws;

    // workspace layout (bytes), total ~131 MB:
    ushort_t* ws_qkvbf = (ushort_t*)(ws);                  // 38,535,168  [25088][768]
    ushort_t* ws_hbf   = (ushort_t*)(ws + 38535168);       // 51,380,224  [25088][1024]
    ushort_t* ws_ybf   = (ushort_t*)(ws + 89915392);       // 12,845,056  [25088][256]
    ushort_t* ws_vt    = (ushort_t*)(ws + 102760448);      // 12,845,056  [8][256][3136]
    ushort_t* ws_attn  = (ushort_t*)(ws + 115605504);      // 12,845,056  [25088][256]
    float*    ws_ymean = (float*)(ws + 128450560);         // 401,408
    float*    ws_qreg  = (float*)(ws + 128851968);         // 401,408
    float*    ws_kreg  = (float*)(ws + 129253376);         // 401,408
    int*      ws_idx   = (int*)(ws + 129654784);           // 6,272
    ushort_t* ws_wqkvT = (ushort_t*)(ws + 129661056);      // 393,216
    ushort_t* ws_woT   = (ushort_t*)(ws + 130054272);      // 131,072
    ushort_t* ws_w1T   = (ushort_t*)(ws + 130185344);      // 524,288
    ushort_t* ws_w2T   = (ushort_t*)(ws + 130709632);      // 524,288

    const int M = NROWS;

    // 0) weights -> bf16 transposed
    wtrans_kernel<<<dim3(768 / 32, 256 / 32), 256, 0, stream>>>(wqkv, ws_wqkvT, 256, 768);
    wtrans_kernel<<<dim3(256 / 32, 256 / 32), 256, 0, stream>>>(wo, ws_woT, 256, 256);
    wtrans_kernel<<<dim3(1024 / 32, 256 / 32), 256, 0, stream>>>(w1, ws_w1T, 256, 1024);
    wtrans_kernel<<<dim3(256 / 32, 1024 / 32), 256, 0, stream>>>(w2, ws_w2T, 1024, 256);
    // 1) y = LN1(x) -> bf16
    ln_kernel<<<M / 4, 256, 0, stream>>>(x, ln1g, ln1b, ws_ybf);
    // 2) routing path, all f32: region means of LN1(x) -> project -> top-4
    ymean_kernel<<<8 * NREG, 256, 0, stream>>>(x, ln1g, ln1b, ws_ymean);
    regproj_kernel<<<8 * NREG, 256, 0, stream>>>(ws_ymean, wqkv, bqkv, ws_qreg, ws_kreg);
    routing_kernel<<<8 * NREG, 64, 0, stream>>>(ws_qreg, ws_kreg, ws_idx);
    // 3) qkv = y @ wqkv + bqkv -> bf16 [M][768], q pre-scaled
    mgemm<0><<<dim3(QKVDIM / 128, M / 128), 256, 0, stream>>>(
        ws_ybf, ws_wqkvT, bqkv, nullptr, nullptr, ws_qkvbf, QKVDIM, CDIM);
    // 4) v^T (bf16, [b][c][3136])
    vtrans_kernel<<<dim3(3136 / 32, 256 / 32, 8), 256, 0, stream>>>(ws_qkvbf, ws_vt);
    // 5) attention -> bf16
    attn2_kernel<<<8 * NREG * NHEADS * 2 / 4, 256, 0, stream>>>(ws_qkvbf, ws_vt, ws_idx, ws_attn);
    // 6) x1 = x + attn @ wo + bo  (f32, into d_out)
    mgemm<1><<<dim3(CDIM / 128, M / 128), 256, 0, stream>>>(
        ws_attn, ws_woT, bo, x, out, nullptr, CDIM, CDIM);
    // 7) z = LN2(x1) -> bf16
    ln_kernel<<<M / 4, 256, 0, stream>>>(out, ln2g, ln2b, ws_ybf);
    // 8) h = gelu(z @ w1 + bm1) -> bf16
    mgemm<2><<<dim3(1024 / 128, M / 128), 256, 0, stream>>>(
        ws_ybf, ws_w1T, bm1, nullptr, nullptr, ws_hbf, 1024, CDIM);
    // 9) out = x1 + h @ w2 + bm2 (f32, in-place residual from d_out)
    mgemm<3><<<dim3(CDIM / 128, M / 128), 256, 0, stream>>>(
        ws_hbf, ws_w2T, bm2, out, out, nullptr, CDIM, 1024);
}

// Round 5
// 321.421 us; speedup vs baseline: 2.9179x; 1.0365x over previous
//
#include <hip/hip_runtime.h>
#include <math.h>

#define CDIM 256
#define QKVDIM 768
#define NHEADS 8
#define DHEAD 32
#define NWIN 7
#define NREG 49
#define TK 4
static constexpr int NROWS = 8 * 56 * 56;  // 25088

typedef __attribute__((ext_vector_type(8))) short s16x8;
typedef __attribute__((ext_vector_type(4))) float f32x4;
typedef __attribute__((ext_vector_type(16))) float f32x16;
typedef unsigned short ushort_t;

union U4 { unsigned u[4]; s16x8 v; };

__device__ __forceinline__ ushort_t bfr(float f) {  // fp32 -> bf16 RNE
    unsigned u = __float_as_uint(f);
    unsigned r = (u + 0x7FFFu + ((u >> 16) & 1u)) >> 16;
    return (ushort_t)r;
}
__device__ __forceinline__ float gelu_f(float x) {
    float u = 0.7978845608028654f * (x + 0.044715f * x * x * x);
    return 0.5f * x * (1.0f + tanhf(u));
}
__device__ __forceinline__ void glds16(const void* g, void* l) {
    __builtin_amdgcn_global_load_lds((const __attribute__((address_space(1))) void*)g,
                                     (__attribute__((address_space(3))) void*)l, 16, 0, 0);
}
template <int N>
__device__ __forceinline__ void waitvm() {
    if constexpr (N == 0) asm volatile("s_waitcnt vmcnt(0)" ::: "memory");
    else if constexpr (N == 3) asm volatile("s_waitcnt vmcnt(3)" ::: "memory");
    else if constexpr (N == 4) asm volatile("s_waitcnt vmcnt(4)" ::: "memory");
}
__device__ __forceinline__ void barrier_raw() {
    asm volatile("s_barrier" ::: "memory");
}
__device__ __forceinline__ f32x16 zero16() {
    f32x16 z;
#pragma unroll
    for (int i = 0; i < 16; i++) z[i] = 0.f;
    return z;
}

// ---------------- LayerNorm: fp32 in -> bf16 out. one wave per row ----------------
__global__ __launch_bounds__(256) void ln_kernel(const float* __restrict__ x,
                                                 const float* __restrict__ g,
                                                 const float* __restrict__ bparam,
                                                 ushort_t* __restrict__ y) {
    int wave = threadIdx.x >> 6, lane = threadIdx.x & 63;
    int row = blockIdx.x * 4 + wave;
    const float4* xr = (const float4*)(x + (size_t)row * CDIM);
    float4 v = xr[lane];
    float s = v.x + v.y + v.z + v.w;
    float s2 = v.x * v.x + v.y * v.y + v.z * v.z + v.w * v.w;
#pragma unroll
    for (int off = 32; off; off >>= 1) {
        s += __shfl_xor(s, off, 64);
        s2 += __shfl_xor(s2, off, 64);
    }
    float mu = s * (1.0f / CDIM);
    float rstd = rsqrtf(s2 * (1.0f / CDIM) - mu * mu + 1e-5f);
    float4 gv = ((const float4*)g)[lane];
    float4 bv = ((const float4*)bparam)[lane];
    ushort4 o;
    o.x = bfr((v.x - mu) * rstd * gv.x + bv.x);
    o.y = bfr((v.y - mu) * rstd * gv.y + bv.y);
    o.z = bfr((v.z - mu) * rstd * gv.z + bv.z);
    o.w = bfr((v.w - mu) * rstd * gv.w + bv.w);
    *(ushort4*)(y + (size_t)row * CDIM + lane * 4) = o;
}

// ---------------- f32 region means of LN1(x): ymean[b*49+r][256] ----------------
__global__ __launch_bounds__(256) void ymean_kernel(const float* __restrict__ x,
                                                    const float* __restrict__ g,
                                                    const float* __restrict__ bparam,
                                                    float* __restrict__ ymean) {
    int blk = blockIdx.x;  // b*49 + rid
    int b = blk / NREG, rid = blk % NREG;
    int ai = rid / NWIN, aj = rid % NWIN;
    int w = threadIdx.x >> 6, lane = threadIdx.x & 63;
    float4 gv = ((const float4*)g)[lane];
    float4 bv = ((const float4*)bparam)[lane];
    float4 acc = {0.f, 0.f, 0.f, 0.f};
    for (int it = 0; it < 16; it++) {
        int t = it * 4 + w;
        size_t row = ((size_t)(b * 56 + ai * 8 + (t >> 3))) * 56 + aj * 8 + (t & 7);
        float4 v = ((const float4*)(x + row * CDIM))[lane];
        float s = v.x + v.y + v.z + v.w;
        float s2 = v.x * v.x + v.y * v.y + v.z * v.z + v.w * v.w;
#pragma unroll
        for (int off = 32; off; off >>= 1) {
            s += __shfl_xor(s, off, 64);
            s2 += __shfl_xor(s2, off, 64);
        }
        float mu = s * (1.0f / CDIM);
        float rstd = rsqrtf(s2 * (1.0f / CDIM) - mu * mu + 1e-5f);
        acc.x += (v.x - mu) * rstd * gv.x + bv.x;
        acc.y += (v.y - mu) * rstd * gv.y + bv.y;
        acc.z += (v.z - mu) * rstd * gv.z + bv.z;
        acc.w += (v.w - mu) * rstd * gv.w + bv.w;
    }
    __shared__ float red[4][CDIM];
    *(float4*)&red[w][lane * 4] = acc;
    __syncthreads();
    if (w == 0) {
        float4 r0 = *(float4*)&red[0][lane * 4];
        float4 r1 = *(float4*)&red[1][lane * 4];
        float4 r2 = *(float4*)&red[2][lane * 4];
        float4 r3 = *(float4*)&red[3][lane * 4];
        float4 o;
        o.x = (r0.x + r1.x + r2.x + r3.x) * (1.0f / 64.0f);
        o.y = (r0.y + r1.y + r2.y + r3.y) * (1.0f / 64.0f);
        o.z = (r0.z + r1.z + r2.z + r3.z) * (1.0f / 64.0f);
        o.w = (r0.w + r1.w + r2.w + r3.w) * (1.0f / 64.0f);
        *(float4*)(ymean + (size_t)blk * CDIM + lane * 4) = o;
    }
}

// ---------------- f32 projection of region means: qreg/kreg ----------------
__global__ __launch_bounds__(256) void regproj_kernel(const float* __restrict__ ymean,
                                                      const float* __restrict__ wqkv,
                                                      const float* __restrict__ bqkv,
                                                      float* __restrict__ qreg,
                                                      float* __restrict__ kreg) {
    int blk = blockIdx.x;
    __shared__ float ym[CDIM];
    ym[threadIdx.x] = ymean[(size_t)blk * CDIM + threadIdx.x];
    __syncthreads();
    int c = threadIdx.x;
    float sq = 0.f, sk = 0.f;
    for (int k = 0; k < CDIM; k++) {
        float yv = ym[k];
        sq = fmaf(yv, wqkv[(size_t)k * QKVDIM + c], sq);
        sk = fmaf(yv, wqkv[(size_t)k * QKVDIM + CDIM + c], sk);
    }
    qreg[(size_t)blk * CDIM + c] = sq + bqkv[c];
    kreg[(size_t)blk * CDIM + c] = sk + bqkv[CDIM + c];
}

// ---------------- weight transpose: f32 [K][N] -> bf16 [N][K] ----------------
__global__ __launch_bounds__(256) void wtrans_kernel(const float* __restrict__ src,
                                                     ushort_t* __restrict__ dst,
                                                     int K, int N) {
    __shared__ float t[32][33];
    int tx = threadIdx.x & 31, ty = threadIdx.x >> 5;
    int n0 = blockIdx.x * 32, k0 = blockIdx.y * 32;
#pragma unroll
    for (int i = 0; i < 4; i++) t[ty + i * 8][tx] = src[(size_t)(k0 + ty + i * 8) * N + n0 + tx];
    __syncthreads();
#pragma unroll
    for (int i = 0; i < 4; i++)
        dst[(size_t)(n0 + ty + i * 8) * K + k0 + tx] = bfr(t[tx][ty + i * 8]);
}

// ---------------- v^T: bf16 qkv v-slice -> vt [b][c=256][t=3136] ----------------
__global__ __launch_bounds__(256) void vtrans_kernel(const ushort_t* __restrict__ qkvbf,
                                                     ushort_t* __restrict__ vt) {
    __shared__ ushort_t t[32][34];
    int tx = threadIdx.x & 31, ty = threadIdx.x >> 5;
    int t0 = blockIdx.x * 32, c0 = blockIdx.y * 32, b = blockIdx.z;
#pragma unroll
    for (int i = 0; i < 4; i++)
        t[ty + i * 8][tx] = qkvbf[((size_t)b * 3136 + t0 + ty + i * 8) * QKVDIM + 512 + c0 + tx];
    __syncthreads();
#pragma unroll
    for (int i = 0; i < 4; i++)
        vt[((size_t)b * CDIM + c0 + ty + i * 8) * 3136 + t0 + tx] = t[tx][ty + i * 8];
}

// ---------------- bf16 MFMA GEMM, double-buffered BK=32, XCD-swizzled ----------
// A: [M][K] bf16, WT: [N][K] bf16. Tile BM x BN, 4 waves (2x2), 16x16x32 MFMA.
// LDS swizzle: 16B slot ^= (row ^ row>>2) & 3, applied stage-side and read-side.
// MODE 0: out bf16 [M][768], cols<256 scaled by 1/sqrt(32)
// MODE 1/3: out f32 = v + bias + res ;  MODE 2: out bf16 = gelu(v + bias)
template <int BM, int BN, int MODE>
__global__ __launch_bounds__(256) void mgemm(const ushort_t* __restrict__ A,
                                             const ushort_t* __restrict__ WT,
                                             const float* __restrict__ bias,
                                             const float* __restrict__ res,
                                             float* __restrict__ outf,
                                             ushort_t* __restrict__ outb,
                                             int N, int K) {
    constexpr int WM = BM / 2, WN = BN / 2, MI = WM / 16, NI = WN / 16;
    constexpr int RA = BM / 64, RB = BN / 64, L = RA + RB;
    __shared__ __align__(16) ushort_t As[2 * BM * 32];
    __shared__ __align__(16) ushort_t Bs[2 * BN * 32];
    const int tid = threadIdx.x, lane = tid & 63, w = tid >> 6;
    const int wm = w >> 1, wn = w & 1;

    // XCD-bijective chunked swizzle (nwg % 8 == 0 for all our grids)
    const int gx = gridDim.x;
    const int nwg = gx * gridDim.y;
    const int bid = blockIdx.y * gx + blockIdx.x;
    const int lbid = (bid & 7) * (nwg >> 3) + (bid >> 3);
    const int tm = (lbid / gx) * BM, tn = (lbid % gx) * BN;

    f32x4 acc[MI][NI];
#pragma unroll
    for (int i = 0; i < MI; i++)
#pragma unroll
        for (int j = 0; j < NI; j++) acc[i][j] = (f32x4){0.f, 0.f, 0.f, 0.f};

    auto stage = [&](int buf, int k0) {
#pragma unroll
        for (int p = 0; p < RA; p++) {
            int row = (p * 4 + w) * 16 + (lane >> 2);
            int slot = lane & 3;
            int mr = (row ^ (row >> 2)) & 3;
            glds16(A + (size_t)(tm + row) * K + k0 + ((slot ^ mr) * 8),
                   (char*)As + buf * BM * 64 + (p * 4 + w) * 1024);
        }
#pragma unroll
        for (int p = 0; p < RB; p++) {
            int row = (p * 4 + w) * 16 + (lane >> 2);
            int slot = lane & 3;
            int mr = (row ^ (row >> 2)) & 3;
            glds16(WT + (size_t)(tn + row) * K + k0 + ((slot ^ mr) * 8),
                   (char*)Bs + buf * BN * 64 + (p * 4 + w) * 1024);
        }
    };

    const int NT = K >> 5;
    const int fr = lane & 15, sl = lane >> 4;
    stage(0, 0);
    for (int kt = 0; kt < NT; ++kt) {
        int cur = kt & 1;
        if (kt + 1 < NT) {
            stage(cur ^ 1, (kt + 1) * 32);
            waitvm<L>();
        } else {
            waitvm<0>();
        }
        barrier_raw();
        s16x8 af[MI], bfv[NI];
#pragma unroll
        for (int i = 0; i < MI; i++) {
            int rowa = wm * WM + i * 16 + fr;
            int ma = (rowa ^ (rowa >> 2)) & 3;
            af[i] = *(const s16x8*)&As[cur * BM * 32 + rowa * 32 + ((sl ^ ma) * 8)];
        }
#pragma unroll
        for (int j = 0; j < NI; j++) {
            int rowb = wn * WN + j * 16 + fr;
            int mb = (rowb ^ (rowb >> 2)) & 3;
            bfv[j] = *(const s16x8*)&Bs[cur * BN * 32 + rowb * 32 + ((sl ^ mb) * 8)];
        }
#pragma unroll
        for (int i = 0; i < MI; i++)
#pragma unroll
            for (int j = 0; j < NI; j++)
                acc[i][j] = __builtin_amdgcn_mfma_f32_16x16x32_bf16(af[i], bfv[j], acc[i][j], 0, 0, 0);
        barrier_raw();
    }

    const int cl = lane & 15, gq = lane >> 4;
#pragma unroll
    for (int j = 0; j < NI; j++) {
        int col = tn + wn * WN + j * 16 + cl;
        float bb = bias[col];
#pragma unroll
        for (int i = 0; i < MI; i++) {
            int rowb = tm + wm * WM + i * 16 + gq * 4;
#pragma unroll
            for (int r = 0; r < 4; r++) {
                float v = acc[i][j][r] + bb;
                size_t off = (size_t)(rowb + r) * N + col;
                if (MODE == 0) {
                    outb[off] = bfr(col < 256 ? v * 0.17677669529663687f : v);
                } else if (MODE == 1 || MODE == 3) {
                    outf[off] = v + res[off];
                } else {
                    outb[off] = bfr(gelu_f(v));
                }
            }
        }
    }
}

// ---------------- routing top-4 (set) ----------------
__global__ __launch_bounds__(64) void routing_kernel(const float* __restrict__ qreg,
                                                     const float* __restrict__ kreg,
                                                     int* __restrict__ idx) {
    int b = blockIdx.x / NREG;
    int row = blockIdx.x % NREG;
    int lane = threadIdx.x;
    float myv = -INFINITY;
    if (lane < NREG) {
        const float* qv = qreg + ((size_t)b * NREG + row) * CDIM;
        const float* kv = kreg + ((size_t)b * NREG + lane) * CDIM;
        float s = 0.f;
        for (int c = 0; c < CDIM; c++) s += qv[c] * kv[c];
        myv = s;
    }
    for (int t = 0; t < TK; t++) {
        float v = myv;
        int ix = lane;
#pragma unroll
        for (int off = 32; off; off >>= 1) {
            float ov = __shfl_xor(v, off, 64);
            int oi = __shfl_xor(ix, off, 64);
            if (ov > v || (ov == v && oi < ix)) { v = ov; ix = oi; }
        }
        if (lane == 0) idx[((size_t)b * NREG + row) * TK + t] = ix;
        if (lane == ix) myv = -INFINITY;
    }
}

// ---------------- MFMA flash attention, fully in-register ----------------
__global__ __launch_bounds__(256) void attn2_kernel(const ushort_t* __restrict__ qk,
                                                    const ushort_t* __restrict__ vt,
                                                    const int* __restrict__ idx,
                                                    ushort_t* __restrict__ outb) {
    int wid = blockIdx.x * 4 + (threadIdx.x >> 6);
    int lane = threadIdx.x & 63;
    int g = lane >> 5, col = lane & 31;
    int qh = wid & 1;
    int h = (wid >> 1) & 7;
    int rr = wid >> 4;  // b*49 + rid
    int rid = rr % NREG, b = rr / NREG;
    int ai = rid / NWIN, aj = rid % NWIN;

    int qtok = qh * 32 + col;
    size_t qrow_g = ((size_t)(b * 56 + ai * 8 + (qtok >> 3))) * 56 + aj * 8 + (qtok & 7);
    const s16x8 bq0 = *(const s16x8*)(qk + qrow_g * QKVDIM + h * 32 + g * 8);
    const s16x8 bq1 = *(const s16x8*)(qk + qrow_g * QKVDIM + h * 32 + 16 + g * 8);

    const int* ip = idx + (size_t)rr * TK;
    int regs[4] = {ip[0], ip[1], ip[2], ip[3]};

    float m_run = -1e30f, l_run = 0.f;
    f32x16 o = zero16();
    const size_t vtrowbase = ((size_t)(b * CDIM + h * 32 + col)) * 3136;

#pragma unroll
    for (int rc = 0; rc < 4; rc++) {
        int reg = regs[rc];
        int rai = reg / NWIN, raj = reg % NWIN;
        s16x8 ka[2][2];
#pragma unroll
        for (int mf = 0; mf < 2; mf++) {
            int ktok = mf * 32 + col;
            size_t krow_g = ((size_t)(b * 56 + rai * 8 + (ktok >> 3))) * 56 + raj * 8 + (ktok & 7);
#pragma unroll
            for (int kd = 0; kd < 2; kd++)
                ka[mf][kd] = *(const s16x8*)(qk + krow_g * QKVDIM + 256 + h * 32 + kd * 16 + g * 8);
        }
        f32x16 s0 = zero16(), s1 = zero16();
        s0 = __builtin_amdgcn_mfma_f32_32x32x16_bf16(ka[0][0], bq0, s0, 0, 0, 0);
        s0 = __builtin_amdgcn_mfma_f32_32x32x16_bf16(ka[0][1], bq1, s0, 0, 0, 0);
        s1 = __builtin_amdgcn_mfma_f32_32x32x16_bf16(ka[1][0], bq0, s1, 0, 0, 0);
        s1 = __builtin_amdgcn_mfma_f32_32x32x16_bf16(ka[1][1], bq1, s1, 0, 0, 0);

        float tmax = -1e30f;
#pragma unroll
        for (int i = 0; i < 16; i++) tmax = fmaxf(tmax, fmaxf(s0[i], s1[i]));
        tmax = fmaxf(tmax, __shfl_xor(tmax, 32, 64));

        float m_new = fmaxf(m_run, tmax);
        float f = __expf(m_run - m_new);
        l_run *= f;
#pragma unroll
        for (int r = 0; r < 16; r++) {
            int orow = (r & 3) + 8 * (r >> 2) + 4 * g;
            float fr = __shfl(f, orow, 64);
            o[r] *= fr;
        }
        m_run = m_new;

        float tsum = 0.f;
#pragma unroll
        for (int i = 0; i < 16; i++) {
            s0[i] = __expf(s0[i] - m_run);
            s1[i] = __expf(s1[i] - m_run);
            tsum += s0[i] + s1[i];
        }
        l_run += tsum + __shfl_xor(tsum, 32, 64);

#define PVSTEP(SS, CC, KS)                                                              \
    {                                                                                   \
        unsigned wa = (unsigned)bfr(SS[CC * 8 + 0]) | ((unsigned)bfr(SS[CC * 8 + 1]) << 16); \
        unsigned wb_ = (unsigned)bfr(SS[CC * 8 + 2]) | ((unsigned)bfr(SS[CC * 8 + 3]) << 16); \
        unsigned wc = (unsigned)bfr(SS[CC * 8 + 4]) | ((unsigned)bfr(SS[CC * 8 + 5]) << 16); \
        unsigned wd = (unsigned)bfr(SS[CC * 8 + 6]) | ((unsigned)bfr(SS[CC * 8 + 7]) << 16); \
        unsigned sxa = (unsigned)__shfl_xor((int)wa, 32, 64);                           \
        unsigned sxb = (unsigned)__shfl_xor((int)wb_, 32, 64);                          \
        unsigned sxc = (unsigned)__shfl_xor((int)wc, 32, 64);                           \
        unsigned sxd = (unsigned)__shfl_xor((int)wd, 32, 64);                           \
        U4 pw;                                                                          \
        pw.u[0] = g ? sxc : wa;                                                         \
        pw.u[1] = g ? sxd : wb_;                                                        \
        pw.u[2] = g ? wc : sxa;                                                         \
        pw.u[3] = g ? wd : sxb;                                                         \
        const s16x8 vb = *(const s16x8*)(vt + vtrowbase + (size_t)(rai * 8 + KS * 2 + g) * 56 + raj * 8); \
        o = __builtin_amdgcn_mfma_f32_32x32x16_bf16(pw.v, vb, o, 0, 0, 0);              \
    }
        PVSTEP(s0, 0, 0)
        PVSTEP(s0, 1, 1)
        PVSTEP(s1, 0, 2)
        PVSTEP(s1, 1, 3)
#undef PVSTEP
    }

#pragma unroll
    for (int r = 0; r < 16; r++) {
        int orow = (r & 3) + 8 * (r >> 2) + 4 * g;
        float lr = __shfl(l_run, orow, 64);
        float val = o[r] / lr;
        int tok = qh * 32 + orow;
        size_t row_g = ((size_t)(b * 56 + ai * 8 + (tok >> 3))) * 56 + aj * 8 + (tok & 7);
        outb[row_g * 256 + h * 32 + col] = bfr(val);
    }
}

extern "C" void kernel_launch(void* const* d_in, const int* in_sizes, int n_in,
                              void* d_out, int out_size, void* d_ws, size_t ws_size,
                              hipStream_t stream) {
    const float* x    = (const float*)d_in[0];
    const float* ln1g = (const float*)d_in[1];
    const float* ln1b = (const float*)d_in[2];
    const float* wqkv = (const float*)d_in[3];
    const float* bqkv = (const float*)d_in[4];
    const float* wo   = (const float*)d_in[5];
    const float* bo   = (const float*)d_in[6];
    const float* ln2g = (const float*)d_in[7];
    const float* ln2b = (const float*)d_in[8];
    const float* w1   = (const float*)d_in[9];
    const float* bm1  = (const float*)d_in[10];
    const float* w2   = (const float*)d_in[11];
    const float* bm2  = (const float*)d_in[12];
    float* out = (float*)d_out;
    char* ws = (char*)d_ws;

    // workspace layout (bytes), total ~131 MB:
    ushort_t* ws_qkvbf = (ushort_t*)(ws);                  // 38,535,168  [25088][768]
    ushort_t* ws_hbf   = (ushort_t*)(ws + 38535168);       // 51,380,224  [25088][1024]
    ushort_t* ws_ybf   = (ushort_t*)(ws + 89915392);       // 12,845,056  [25088][256]
    ushort_t* ws_vt    = (ushort_t*)(ws + 102760448);      // 12,845,056  [8][256][3136]
    ushort_t* ws_attn  = (ushort_t*)(ws + 115605504);      // 12,845,056  [25088][256]
    float*    ws_ymean = (float*)(ws + 128450560);         // 401,408
    float*    ws_qreg  = (float*)(ws + 128851968);         // 401,408
    float*    ws_kreg  = (float*)(ws + 129253376);         // 401,408
    int*      ws_idx   = (int*)(ws + 129654784);           // 6,272
    ushort_t* ws_wqkvT = (ushort_t*)(ws + 129661056);      // 393,216
    ushort_t* ws_woT   = (ushort_t*)(ws + 130054272);      // 131,072
    ushort_t* ws_w1T   = (ushort_t*)(ws + 130185344);      // 524,288
    ushort_t* ws_w2T   = (ushort_t*)(ws + 130709632);      // 524,288

    const int M = NROWS;

    // 0) weights -> bf16 transposed
    wtrans_kernel<<<dim3(768 / 32, 256 / 32), 256, 0, stream>>>(wqkv, ws_wqkvT, 256, 768);
    wtrans_kernel<<<dim3(256 / 32, 256 / 32), 256, 0, stream>>>(wo, ws_woT, 256, 256);
    wtrans_kernel<<<dim3(1024 / 32, 256 / 32), 256, 0, stream>>>(w1, ws_w1T, 256, 1024);
    wtrans_kernel<<<dim3(256 / 32, 1024 / 32), 256, 0, stream>>>(w2, ws_w2T, 1024, 256);
    // 1) y = LN1(x) -> bf16
    ln_kernel<<<M / 4, 256, 0, stream>>>(x, ln1g, ln1b, ws_ybf);
    // 2) routing path, all f32
    ymean_kernel<<<8 * NREG, 256, 0, stream>>>(x, ln1g, ln1b, ws_ymean);
    regproj_kernel<<<8 * NREG, 256, 0, stream>>>(ws_ymean, wqkv, bqkv, ws_qreg, ws_kreg);
    routing_kernel<<<8 * NREG, 64, 0, stream>>>(ws_qreg, ws_kreg, ws_idx);
    // 3) qkv = y @ wqkv + bqkv -> bf16 [M][768], q pre-scaled   (grid 1176)
    mgemm<128, 128, 0><<<dim3(QKVDIM / 128, M / 128), 256, 0, stream>>>(
        ws_ybf, ws_wqkvT, bqkv, nullptr, nullptr, ws_qkvbf, QKVDIM, CDIM);
    // 4) v^T (bf16, [b][c][3136])
    vtrans_kernel<<<dim3(3136 / 32, 256 / 32, 8), 256, 0, stream>>>(ws_qkvbf, ws_vt);
    // 5) attention -> bf16
    attn2_kernel<<<8 * NREG * NHEADS * 2 / 4, 256, 0, stream>>>(ws_qkvbf, ws_vt, ws_idx, ws_attn);
    // 6) x1 = x + attn @ wo + bo  (f32, into d_out)   (grid 784)
    mgemm<128, 64, 1><<<dim3(CDIM / 64, M / 128), 256, 0, stream>>>(
        ws_attn, ws_woT, bo, x, out, nullptr, CDIM, CDIM);
    // 7) z = LN2(x1) -> bf16
    ln_kernel<<<M / 4, 256, 0, stream>>>(out, ln2g, ln2b, ws_ybf);
    // 8) h = gelu(z @ w1 + bm1) -> bf16   (grid 1568)
    mgemm<128, 128, 2><<<dim3(1024 / 128, M / 128), 256, 0, stream>>>(
        ws_ybf, ws_w1T, bm1, nullptr, nullptr, ws_hbf, 1024, CDIM);
    // 9) out = x1 + h @ w2 + bm2 (f32, in-place residual from d_out)   (grid 784)
    mgemm<128, 64, 3><<<dim3(CDIM / 64, M / 128), 256, 0, stream>>>(
        ws_hbf, ws_w2T, bm2, out, out, nullptr, CDIM, 1024);
}

// Round 7
// 314.372 us; speedup vs baseline: 2.9833x; 1.0224x over previous
//
#include <hip/hip_runtime.h>
#include <math.h>

#define CDIM 256
#define QKVDIM 768
#define NHEADS 8
#define DHEAD 32
#define NWIN 7
#define NREG 49
#define TK 4
static constexpr int NROWS = 8 * 56 * 56;  // 25088

typedef __attribute__((ext_vector_type(8))) short s16x8;
typedef __attribute__((ext_vector_type(4))) float f32x4;
typedef __attribute__((ext_vector_type(16))) float f32x16;
typedef unsigned short ushort_t;

union U4 { unsigned u[4]; s16x8 v; };

__device__ __forceinline__ ushort_t bfr(float f) {  // fp32 -> bf16 RNE
    unsigned u = __float_as_uint(f);
    unsigned r = (u + 0x7FFFu + ((u >> 16) & 1u)) >> 16;
    return (ushort_t)r;
}
__device__ __forceinline__ float gelu_f(float x) {
    float u = 0.7978845608028654f * (x + 0.044715f * x * x * x);
    float e = __expf(2.0f * u);                 // tanh(u) = 1 - 2/(e^{2u}+1)
    float t = 1.0f - __fdividef(2.0f, e + 1.0f);
    return 0.5f * x * (1.0f + t);
}
__device__ __forceinline__ void glds16(const void* g, void* l) {
    __builtin_amdgcn_global_load_lds((const __attribute__((address_space(1))) void*)g,
                                     (__attribute__((address_space(3))) void*)l, 16, 0, 0);
}
template <int N>
__device__ __forceinline__ void waitvm() {
    if constexpr (N == 0) asm volatile("s_waitcnt vmcnt(0)" ::: "memory");
    else if constexpr (N == 3) asm volatile("s_waitcnt vmcnt(3)" ::: "memory");
    else if constexpr (N == 4) asm volatile("s_waitcnt vmcnt(4)" ::: "memory");
}
__device__ __forceinline__ void barrier_raw() {
    asm volatile("s_barrier" ::: "memory");
}
__device__ __forceinline__ f32x16 zero16() {
    f32x16 z;
#pragma unroll
    for (int i = 0; i < 16; i++) z[i] = 0.f;
    return z;
}

// ---------------- LayerNorm: fp32 in -> bf16 out. one wave per row ----------------
__global__ __launch_bounds__(256) void ln_kernel(const float* __restrict__ x,
                                                 const float* __restrict__ g,
                                                 const float* __restrict__ bparam,
                                                 ushort_t* __restrict__ y) {
    int wave = threadIdx.x >> 6, lane = threadIdx.x & 63;
    int row = blockIdx.x * 4 + wave;
    const float4* xr = (const float4*)(x + (size_t)row * CDIM);
    float4 v = xr[lane];
    float s = v.x + v.y + v.z + v.w;
    float s2 = v.x * v.x + v.y * v.y + v.z * v.z + v.w * v.w;
#pragma unroll
    for (int off = 32; off; off >>= 1) {
        s += __shfl_xor(s, off, 64);
        s2 += __shfl_xor(s2, off, 64);
    }
    float mu = s * (1.0f / CDIM);
    float rstd = rsqrtf(s2 * (1.0f / CDIM) - mu * mu + 1e-5f);
    float4 gv = ((const float4*)g)[lane];
    float4 bv = ((const float4*)bparam)[lane];
    ushort4 o;
    o.x = bfr((v.x - mu) * rstd * gv.x + bv.x);
    o.y = bfr((v.y - mu) * rstd * gv.y + bv.y);
    o.z = bfr((v.z - mu) * rstd * gv.z + bv.z);
    o.w = bfr((v.w - mu) * rstd * gv.w + bv.w);
    *(ushort4*)(y + (size_t)row * CDIM + lane * 4) = o;
}

// ---------------- f32 region means of LN1(x): ymean[b*49+r][256] ----------------
__global__ __launch_bounds__(256) void ymean_kernel(const float* __restrict__ x,
                                                    const float* __restrict__ g,
                                                    const float* __restrict__ bparam,
                                                    float* __restrict__ ymean) {
    int blk = blockIdx.x;  // b*49 + rid
    int b = blk / NREG, rid = blk % NREG;
    int ai = rid / NWIN, aj = rid % NWIN;
    int w = threadIdx.x >> 6, lane = threadIdx.x & 63;
    float4 gv = ((const float4*)g)[lane];
    float4 bv = ((const float4*)bparam)[lane];
    float4 acc = {0.f, 0.f, 0.f, 0.f};
    for (int it = 0; it < 16; it++) {
        int t = it * 4 + w;
        size_t row = ((size_t)(b * 56 + ai * 8 + (t >> 3))) * 56 + aj * 8 + (t & 7);
        float4 v = ((const float4*)(x + row * CDIM))[lane];
        float s = v.x + v.y + v.z + v.w;
        float s2 = v.x * v.x + v.y * v.y + v.z * v.z + v.w * v.w;
#pragma unroll
        for (int off = 32; off; off >>= 1) {
            s += __shfl_xor(s, off, 64);
            s2 += __shfl_xor(s2, off, 64);
        }
        float mu = s * (1.0f / CDIM);
        float rstd = rsqrtf(s2 * (1.0f / CDIM) - mu * mu + 1e-5f);
        acc.x += (v.x - mu) * rstd * gv.x + bv.x;
        acc.y += (v.y - mu) * rstd * gv.y + bv.y;
        acc.z += (v.z - mu) * rstd * gv.z + bv.z;
        acc.w += (v.w - mu) * rstd * gv.w + bv.w;
    }
    __shared__ float red[4][CDIM];
    *(float4*)&red[w][lane * 4] = acc;
    __syncthreads();
    if (w == 0) {
        float4 r0 = *(float4*)&red[0][lane * 4];
        float4 r1 = *(float4*)&red[1][lane * 4];
        float4 r2 = *(float4*)&red[2][lane * 4];
        float4 r3 = *(float4*)&red[3][lane * 4];
        float4 o;
        o.x = (r0.x + r1.x + r2.x + r3.x) * (1.0f / 64.0f);
        o.y = (r0.y + r1.y + r2.y + r3.y) * (1.0f / 64.0f);
        o.z = (r0.z + r1.z + r2.z + r3.z) * (1.0f / 64.0f);
        o.w = (r0.w + r1.w + r2.w + r3.w) * (1.0f / 64.0f);
        *(float4*)(ymean + (size_t)blk * CDIM + lane * 4) = o;
    }
}

// ---------------- f32 projection of region means: qreg/kreg ----------------
__global__ __launch_bounds__(256) void regproj_kernel(const float* __restrict__ ymean,
                                                      const float* __restrict__ wqkv,
                                                      const float* __restrict__ bqkv,
                                                      float* __restrict__ qreg,
                                                      float* __restrict__ kreg) {
    int blk = blockIdx.x;
    __shared__ float ym[CDIM];
    ym[threadIdx.x] = ymean[(size_t)blk * CDIM + threadIdx.x];
    __syncthreads();
    int c = threadIdx.x;
    float sq = 0.f, sk = 0.f;
    for (int k = 0; k < CDIM; k++) {
        float yv = ym[k];
        sq = fmaf(yv, wqkv[(size_t)k * QKVDIM + c], sq);
        sk = fmaf(yv, wqkv[(size_t)k * QKVDIM + CDIM + c], sk);
    }
    qreg[(size_t)blk * CDIM + c] = sq + bqkv[c];
    kreg[(size_t)blk * CDIM + c] = sk + bqkv[CDIM + c];
}

// ---------------- weight transpose: f32 [K][N] -> bf16 [N][K] ----------------
__global__ __launch_bounds__(256) void wtrans_kernel(const float* __restrict__ src,
                                                     ushort_t* __restrict__ dst,
                                                     int K, int N) {
    __shared__ float t[32][33];
    int tx = threadIdx.x & 31, ty = threadIdx.x >> 5;
    int n0 = blockIdx.x * 32, k0 = blockIdx.y * 32;
#pragma unroll
    for (int i = 0; i < 4; i++) t[ty + i * 8][tx] = src[(size_t)(k0 + ty + i * 8) * N + n0 + tx];
    __syncthreads();
#pragma unroll
    for (int i = 0; i < 4; i++)
        dst[(size_t)(n0 + ty + i * 8) * K + k0 + tx] = bfr(t[tx][ty + i * 8]);
}

// ---------------- v^T: bf16 qkv v-slice -> vt [b][c=256][t=3136] ----------------
__global__ __launch_bounds__(256) void vtrans_kernel(const ushort_t* __restrict__ qkvbf,
                                                     ushort_t* __restrict__ vt) {
    __shared__ ushort_t t[32][34];
    int tx = threadIdx.x & 31, ty = threadIdx.x >> 5;
    int t0 = blockIdx.x * 32, c0 = blockIdx.y * 32, b = blockIdx.z;
#pragma unroll
    for (int i = 0; i < 4; i++)
        t[ty + i * 8][tx] = qkvbf[((size_t)b * 3136 + t0 + ty + i * 8) * QKVDIM + 512 + c0 + tx];
    __syncthreads();
#pragma unroll
    for (int i = 0; i < 4; i++)
        vt[((size_t)b * CDIM + c0 + ty + i * 8) * 3136 + t0 + tx] = t[tx][ty + i * 8];
}

// ---------------- bf16 MFMA GEMM, double-buffered BK=32, XCD-swizzled ----------
// LDS swizzle: 16B slot ^= (row>>1)&3 (2-way free), stage-side and read-side.
// MODE 0: out bf16 [M][768], cols<256 scaled (LDS-staged 16B stores)
// MODE 1/3: out f32 = v + bias + res (direct, 64B-contiguous)
// MODE 2: out bf16 = gelu(v + bias) (LDS-staged 16B stores)
template <int BM, int BN, int MODE>
__global__ __launch_bounds__(256) void mgemm(const ushort_t* __restrict__ A,
                                             const ushort_t* __restrict__ WT,
                                             const float* __restrict__ bias,
                                             const float* __restrict__ res,
                                             float* __restrict__ outf,
                                             ushort_t* __restrict__ outb,
                                             int N, int K) {
    constexpr int WM = BM / 2, WN = BN / 2, MI = WM / 16, NI = WN / 16;
    constexpr int RA = BM / 64, RB = BN / 64, L = RA + RB;
    __shared__ __align__(16) char smem[2 * (BM + BN) * 64];
    ushort_t* As = (ushort_t*)smem;                   // 2 bufs x BM x 32
    ushort_t* Bs = (ushort_t*)(smem + 2 * BM * 64);   // 2 bufs x BN x 32
    ushort_t* Cs = (ushort_t*)smem;                   // epilogue staging (64 x 136)
    const int tid = threadIdx.x, lane = tid & 63, w = tid >> 6;
    const int wm = w >> 1, wn = w & 1;

    // XCD-bijective chunked swizzle (nwg % 8 == 0 for all our grids)
    const int gx = gridDim.x;
    const int nwg = gx * gridDim.y;
    const int bid = blockIdx.y * gx + blockIdx.x;
    const int lbid = (bid & 7) * (nwg >> 3) + (bid >> 3);
    const int tm = (lbid / gx) * BM, tn = (lbid % gx) * BN;

    f32x4 acc[MI][NI];
#pragma unroll
    for (int i = 0; i < MI; i++)
#pragma unroll
        for (int j = 0; j < NI; j++) acc[i][j] = (f32x4){0.f, 0.f, 0.f, 0.f};

    auto stage = [&](int buf, int k0) {
#pragma unroll
        for (int p = 0; p < RA; p++) {
            int row = (p * 4 + w) * 16 + (lane >> 2);
            int slot = lane & 3;
            int mr = (row >> 1) & 3;
            glds16(A + (size_t)(tm + row) * K + k0 + ((slot ^ mr) * 8),
                   (char*)As + buf * BM * 64 + (p * 4 + w) * 1024);
        }
#pragma unroll
        for (int p = 0; p < RB; p++) {
            int row = (p * 4 + w) * 16 + (lane >> 2);
            int slot = lane & 3;
            int mr = (row >> 1) & 3;
            glds16(WT + (size_t)(tn + row) * K + k0 + ((slot ^ mr) * 8),
                   (char*)Bs + buf * BN * 64 + (p * 4 + w) * 1024);
        }
    };

    const int NT = K >> 5;
    const int fr = lane & 15, sl = lane >> 4;
    stage(0, 0);
    for (int kt = 0; kt < NT; ++kt) {
        int cur = kt & 1;
        if (kt + 1 < NT) {
            stage(cur ^ 1, (kt + 1) * 32);
            waitvm<L>();
        } else {
            waitvm<0>();
        }
        barrier_raw();
        s16x8 af[MI], bfv[NI];
#pragma unroll
        for (int i = 0; i < MI; i++) {
            int rowa = wm * WM + i * 16 + fr;
            int ma = (rowa >> 1) & 3;
            af[i] = *(const s16x8*)&As[cur * BM * 32 + rowa * 32 + ((sl ^ ma) * 8)];
        }
#pragma unroll
        for (int j = 0; j < NI; j++) {
            int rowb = wn * WN + j * 16 + fr;
            int mb = (rowb >> 1) & 3;
            bfv[j] = *(const s16x8*)&Bs[cur * BN * 32 + rowb * 32 + ((sl ^ mb) * 8)];
        }
#pragma unroll
        for (int i = 0; i < MI; i++)
#pragma unroll
            for (int j = 0; j < NI; j++)
                acc[i][j] = __builtin_amdgcn_mfma_f32_16x16x32_bf16(af[i], bfv[j], acc[i][j], 0, 0, 0);
        barrier_raw();
    }

    const int cl = lane & 15, gq = lane >> 4;
    if constexpr (MODE == 0 || MODE == 2) {
        // LDS-staged epilogue: two 64-row phases; 16B contiguous stores.
        // (BN == 128 for both bf16 modes)
#pragma unroll
        for (int hh = 0; hh < 2; hh++) {
            if (wm == hh) {
#pragma unroll
                for (int j = 0; j < NI; j++) {
                    int lcol = wn * WN + j * 16 + cl;
                    int col = tn + lcol;
                    float bb = bias[col];
#pragma unroll
                    for (int i = 0; i < MI; i++) {
#pragma unroll
                        for (int r = 0; r < 4; r++) {
                            float v = acc[i][j][r] + bb;
                            ushort_t ov;
                            if (MODE == 0)
                                ov = bfr(col < 256 ? v * 0.17677669529663687f : v);
                            else
                                ov = bfr(gelu_f(v));
                            Cs[(i * 16 + gq * 4 + r) * 136 + lcol] = ov;
                        }
                    }
                }
            }
            __syncthreads();
            {
                int row_l = tid >> 2;         // 0..63
                int cb = (tid & 3) * 8;       // 4 lanes cover 32 cols = 64B
                ushort_t* gbase = outb + (size_t)(tm + hh * 64 + row_l) * N + tn;
#pragma unroll
                for (int c = 0; c < 4; c++) {
                    int col = cb + c * 32;
                    *(s16x8*)(gbase + col) = *(const s16x8*)&Cs[row_l * 136 + col];
                }
            }
            if (hh == 0) __syncthreads();
        }
    } else {
#pragma unroll
        for (int j = 0; j < NI; j++) {
            int col = tn + wn * WN + j * 16 + cl;
            float bb = bias[col];
#pragma unroll
            for (int i = 0; i < MI; i++) {
                int rowb = tm + wm * WM + i * 16 + gq * 4;
#pragma unroll
                for (int r = 0; r < 4; r++) {
                    float v = acc[i][j][r] + bb;
                    size_t off = (size_t)(rowb + r) * N + col;
                    outf[off] = v + res[off];
                }
            }
        }
    }
}

// ---------------- routing top-4 (set) ----------------
__global__ __launch_bounds__(64) void routing_kernel(const float* __restrict__ qreg,
                                                     const float* __restrict__ kreg,
                                                     int* __restrict__ idx) {
    int b = blockIdx.x / NREG;
    int row = blockIdx.x % NREG;
    int lane = threadIdx.x;
    float myv = -INFINITY;
    if (lane < NREG) {
        const float* qv = qreg + ((size_t)b * NREG + row) * CDIM;
        const float* kv = kreg + ((size_t)b * NREG + lane) * CDIM;
        float s = 0.f;
        for (int c = 0; c < CDIM; c++) s += qv[c] * kv[c];
        myv = s;
    }
    for (int t = 0; t < TK; t++) {
        float v = myv;
        int ix = lane;
#pragma unroll
        for (int off = 32; off; off >>= 1) {
            float ov = __shfl_xor(v, off, 64);
            int oi = __shfl_xor(ix, off, 64);
            if (ov > v || (ov == v && oi < ix)) { v = ov; ix = oi; }
        }
        if (lane == 0) idx[((size_t)b * NREG + row) * TK + t] = ix;
        if (lane == ix) myv = -INFINITY;
    }
}

// ---------------- MFMA flash attention, fully in-register ----------------
__global__ __launch_bounds__(256) void attn2_kernel(const ushort_t* __restrict__ qk,
                                                    const ushort_t* __restrict__ vt,
                                                    const int* __restrict__ idx,
                                                    ushort_t* __restrict__ outb) {
    int wid = blockIdx.x * 4 + (threadIdx.x >> 6);
    int lane = threadIdx.x & 63;
    int g = lane >> 5, col = lane & 31;
    int qh = wid & 1;
    int h = (wid >> 1) & 7;
    int rr = wid >> 4;  // b*49 + rid
    int rid = rr % NREG, b = rr / NREG;
    int ai = rid / NWIN, aj = rid % NWIN;

    int qtok = qh * 32 + col;
    size_t qrow_g = ((size_t)(b * 56 + ai * 8 + (qtok >> 3))) * 56 + aj * 8 + (qtok & 7);
    const s16x8 bq0 = *(const s16x8*)(qk + qrow_g * QKVDIM + h * 32 + g * 8);
    const s16x8 bq1 = *(const s16x8*)(qk + qrow_g * QKVDIM + h * 32 + 16 + g * 8);

    const int* ip = idx + (size_t)rr * TK;
    int regs[4] = {ip[0], ip[1], ip[2], ip[3]};

    float m_run = -1e30f, l_run = 0.f;
    f32x16 o = zero16();
    const size_t vtrowbase = ((size_t)(b * CDIM + h * 32 + col)) * 3136;

#pragma unroll
    for (int rc = 0; rc < 4; rc++) {
        int reg = regs[rc];
        int rai = reg / NWIN, raj = reg % NWIN;
        s16x8 ka[2][2];
#pragma unroll
        for (int mf = 0; mf < 2; mf++) {
            int ktok = mf * 32 + col;
            size_t krow_g = ((size_t)(b * 56 + rai * 8 + (ktok >> 3))) * 56 + raj * 8 + (ktok & 7);
#pragma unroll
            for (int kd = 0; kd < 2; kd++)
                ka[mf][kd] = *(const s16x8*)(qk + krow_g * QKVDIM + 256 + h * 32 + kd * 16 + g * 8);
        }
        f32x16 s0 = zero16(), s1 = zero16();
        s0 = __builtin_amdgcn_mfma_f32_32x32x16_bf16(ka[0][0], bq0, s0, 0, 0, 0);
        s0 = __builtin_amdgcn_mfma_f32_32x32x16_bf16(ka[0][1], bq1, s0, 0, 0, 0);
        s1 = __builtin_amdgcn_mfma_f32_32x32x16_bf16(ka[1][0], bq0, s1, 0, 0, 0);
        s1 = __builtin_amdgcn_mfma_f32_32x32x16_bf16(ka[1][1], bq1, s1, 0, 0, 0);

        float tmax = -1e30f;
#pragma unroll
        for (int i = 0; i < 16; i++) tmax = fmaxf(tmax, fmaxf(s0[i], s1[i]));
        tmax = fmaxf(tmax, __shfl_xor(tmax, 32, 64));

        float m_new = fmaxf(m_run, tmax);
        float f = __expf(m_run - m_new);
        l_run *= f;
#pragma unroll
        for (int r = 0; r < 16; r++) {
            int orow = (r & 3) + 8 * (r >> 2) + 4 * g;
            float fr = __shfl(f, orow, 64);
            o[r] *= fr;
        }
        m_run = m_new;

        float tsum = 0.f;
#pragma unroll
        for (int i = 0; i < 16; i++) {
            s0[i] = __expf(s0[i] - m_run);
            s1[i] = __expf(s1[i] - m_run);
            tsum += s0[i] + s1[i];
        }
        l_run += tsum + __shfl_xor(tsum, 32, 64);

#define PVSTEP(SS, CC, KS)                                                              \
    {                                                                                   \
        unsigned wa = (unsigned)bfr(SS[CC * 8 + 0]) | ((unsigned)bfr(SS[CC * 8 + 1]) << 16); \
        unsigned wb_ = (unsigned)bfr(SS[CC * 8 + 2]) | ((unsigned)bfr(SS[CC * 8 + 3]) << 16); \
        unsigned wc = (unsigned)bfr(SS[CC * 8 + 4]) | ((unsigned)bfr(SS[CC * 8 + 5]) << 16); \
        unsigned wd = (unsigned)bfr(SS[CC * 8 + 6]) | ((unsigned)bfr(SS[CC * 8 + 7]) << 16); \
        unsigned sxa = (unsigned)__shfl_xor((int)wa, 32, 64);                           \
        unsigned sxb = (unsigned)__shfl_xor((int)wb_, 32, 64);                          \
        unsigned sxc = (unsigned)__shfl_xor((int)wc, 32, 64);                           \
        unsigned sxd = (unsigned)__shfl_xor((int)wd, 32, 64);                           \
        U4 pw;                                                                          \
        pw.u[0] = g ? sxc : wa;                                                         \
        pw.u[1] = g ? sxd : wb_;                                                        \
        pw.u[2] = g ? wc : sxa;                                                         \
        pw.u[3] = g ? wd : sxb;                                                         \
        const s16x8 vb = *(const s16x8*)(vt + vtrowbase + (size_t)(rai * 8 + KS * 2 + g) * 56 + raj * 8); \
        o = __builtin_amdgcn_mfma_f32_32x32x16_bf16(pw.v, vb, o, 0, 0, 0);              \
    }
        PVSTEP(s0, 0, 0)
        PVSTEP(s0, 1, 1)
        PVSTEP(s1, 0, 2)
        PVSTEP(s1, 1, 3)
#undef PVSTEP
    }

#pragma unroll
    for (int r = 0; r < 16; r++) {
        int orow = (r & 3) + 8 * (r >> 2) + 4 * g;
        float lr = __shfl(l_run, orow, 64);
        float val = o[r] / lr;
        int tok = qh * 32 + orow;
        size_t row_g = ((size_t)(b * 56 + ai * 8 + (tok >> 3))) * 56 + aj * 8 + (tok & 7);
        outb[row_g * 256 + h * 32 + col] = bfr(val);
    }
}

extern "C" void kernel_launch(void* const* d_in, const int* in_sizes, int n_in,
                              void* d_out, int out_size, void* d_ws, size_t ws_size,
                              hipStream_t stream) {
    const float* x    = (const float*)d_in[0];
    const float* ln1g = (const float*)d_in[1];
    const float* ln1b = (const float*)d_in[2];
    const float* wqkv = (const float*)d_in[3];
    const float* bqkv = (const float*)d_in[4];
    const float* wo   = (const float*)d_in[5];
    const float* bo   = (const float*)d_in[6];
    const float* ln2g = (const float*)d_in[7];
    const float* ln2b = (const float*)d_in[8];
    const float* w1   = (const float*)d_in[9];
    const float* bm1  = (const float*)d_in[10];
    const float* w2   = (const float*)d_in[11];
    const float* bm2  = (const float*)d_in[12];
    float* out = (float*)d_out;
    char* ws = (char*)d_ws;

    // workspace layout (bytes), total ~131 MB:
    ushort_t* ws_qkvbf = (ushort_t*)(ws);                  // 38,535,168  [25088][768]
    ushort_t* ws_hbf   = (ushort_t*)(ws + 38535168);       // 51,380,224  [25088][1024]
    ushort_t* ws_ybf   = (ushort_t*)(ws + 89915392);       // 12,845,056  [25088][256]
    ushort_t* ws_vt    = (ushort_t*)(ws + 102760448);      // 12,845,056  [8][256][3136]
    ushort_t* ws_attn  = (ushort_t*)(ws + 115605504);      // 12,845,056  [25088][256]
    float*    ws_ymean = (float*)(ws + 128450560);         // 401,408
    float*    ws_qreg  = (float*)(ws + 128851968);         // 401,408
    float*    ws_kreg  = (float*)(ws + 129253376);         // 401,408
    int*      ws_idx   = (int*)(ws + 129654784);           // 6,272
    ushort_t* ws_wqkvT = (ushort_t*)(ws + 129661056);      // 393,216
    ushort_t* ws_woT   = (ushort_t*)(ws + 130054272);      // 131,072
    ushort_t* ws_w1T   = (ushort_t*)(ws + 130185344);      // 524,288
    ushort_t* ws_w2T   = (ushort_t*)(ws + 130709632);      // 524,288

    const int M = NROWS;

    // 0) weights -> bf16 transposed
    wtrans_kernel<<<dim3(768 / 32, 256 / 32), 256, 0, stream>>>(wqkv, ws_wqkvT, 256, 768);
    wtrans_kernel<<<dim3(256 / 32, 256 / 32), 256, 0, stream>>>(wo, ws_woT, 256, 256);
    wtrans_kernel<<<dim3(1024 / 32, 256 / 32), 256, 0, stream>>>(w1, ws_w1T, 256, 1024);
    wtrans_kernel<<<dim3(256 / 32, 1024 / 32), 256, 0, stream>>>(w2, ws_w2T, 1024, 256);
    // 1) y = LN1(x) -> bf16
    ln_kernel<<<M / 4, 256, 0, stream>>>(x, ln1g, ln1b, ws_ybf);
    // 2) routing path, all f32
    ymean_kernel<<<8 * NREG, 256, 0, stream>>>(x, ln1g, ln1b, ws_ymean);
    regproj_kernel<<<8 * NREG, 256, 0, stream>>>(ws_ymean, wqkv, bqkv, ws_qreg, ws_kreg);
    routing_kernel<<<8 * NREG, 64, 0, stream>>>(ws_qreg, ws_kreg, ws_idx);
    // 3) qkv = y @ wqkv + bqkv -> bf16 [M][768], q pre-scaled   (grid 1176)
    mgemm<128, 128, 0><<<dim3(QKVDIM / 128, M / 128), 256, 0, stream>>>(
        ws_ybf, ws_wqkvT, bqkv, nullptr, nullptr, ws_qkvbf, QKVDIM, CDIM);
    // 4) v^T (bf16, [b][c][3136])
    vtrans_kernel<<<dim3(3136 / 32, 256 / 32, 8), 256, 0, stream>>>(ws_qkvbf, ws_vt);
    // 5) attention -> bf16
    attn2_kernel<<<8 * NREG * NHEADS * 2 / 4, 256, 0, stream>>>(ws_qkvbf, ws_vt, ws_idx, ws_attn);
    // 6) x1 = x + attn @ wo + bo  (f32, into d_out)   (grid 784)
    mgemm<128, 64, 1><<<dim3(CDIM / 64, M / 128), 256, 0, stream>>>(
        ws_attn, ws_woT, bo, x, out, nullptr, CDIM, CDIM);
    // 7) z = LN2(x1) -> bf16
    ln_kernel<<<M / 4, 256, 0, stream>>>(out, ln2g, ln2b, ws_ybf);
    // 8) h = gelu(z @ w1 + bm1) -> bf16   (grid 1568)
    mgemm<128, 128, 2><<<dim3(1024 / 128, M / 128), 256, 0, stream>>>(
        ws_ybf, ws_w1T, bm1, nullptr, nullptr, ws_hbf, 1024, CDIM);
    // 9) out = x1 + h @ w2 + bm2 (f32, in-place residual from d_out)   (grid 784)
    mgemm<128, 64, 3><<<dim3(CDIM / 64, M / 128), 256, 0, stream>>>(
        ws_hbf, ws_w2T, bm2, out, out, nullptr, CDIM, 1024);
}